// Round 5
// baseline (406.909 us; speedup 1.0000x reference)
//
#include <hip/hip_runtime.h>

#define BB 32
#define CC 512
#define HWN 1024
#define DD 64
#define OO 640  // 2*DD + CC

typedef short bf16x8 __attribute__((ext_vector_type(8)));
typedef float f32x4 __attribute__((ext_vector_type(4)));
typedef __attribute__((address_space(1))) const void gvoid;
typedef __attribute__((address_space(3))) void svoid;

__device__ __forceinline__ void gload_lds16(const void* g, void* l) {
    __builtin_amdgcn_global_load_lds((gvoid*)g, (svoid*)l, 16, 0, 0);
}

__device__ __forceinline__ unsigned short f2bf(float f) {
    unsigned int u = __float_as_uint(f);
    unsigned int r = u + 0x7FFFu + ((u >> 16) & 1u);  // RNE
    return (unsigned short)(r >> 16);
}
__device__ __forceinline__ float bf2f(unsigned short h) {
    return __uint_as_float(((unsigned int)h) << 16);
}

// ---------------- f32 -> bf16 convert, all 3 weight matrices in one launch ----
__global__ __launch_bounds__(256) void cvt3_kernel(const float* __restrict__ a,
                                                   const float* __restrict__ b,
                                                   const float* __restrict__ c,
                                                   unsigned short* __restrict__ oa,
                                                   unsigned short* __restrict__ ob,
                                                   unsigned short* __restrict__ oc) {
    const int n1 = OO * CC, n2 = CC * CC;
    int i = blockIdx.x * 256 + threadIdx.x;
    if (i < n1)            oa[i] = f2bf(a[i]);
    else if (i < n1 + n2)  ob[i - n1] = f2bf(b[i - n1]);
    else                   oc[i - n1 - n2] = f2bf(c[i - n1 - n2]);
}

// ---------------- BN stats: one block per channel (fp32 input, bn1 only) ------
template <bool INBF16>
__global__ __launch_bounds__(256) void bn_stats_kernel(const void* __restrict__ xv,
                                                       float* __restrict__ mean,
                                                       float* __restrict__ rstd) {
    int c = blockIdx.x;
    int t = threadIdx.x;
    float s = 0.f, s2 = 0.f;
    if (INBF16) {
        const unsigned int* x = (const unsigned int*)xv;  // 2 bf16 per uint
        for (int b = 0; b < BB; ++b) {
            const unsigned int* p = x + ((size_t)b * CC + c) * (HWN / 2);
#pragma unroll
            for (int i = 0; i < 2; ++i) {
                unsigned int w = p[t + i * 256];
                float v0 = bf2f((unsigned short)(w & 0xffffu));
                float v1 = bf2f((unsigned short)(w >> 16));
                s += v0 + v1; s2 += v0 * v0 + v1 * v1;
            }
        }
    } else {
        const float* x = (const float*)xv;
        for (int b = 0; b < BB; ++b) {
            const float* p = x + ((size_t)b * CC + c) * HWN;
#pragma unroll
            for (int i = 0; i < 4; ++i) {
                float v = p[t + i * 256];
                s += v; s2 += v * v;
            }
        }
    }
    for (int off = 32; off > 0; off >>= 1) {
        s  += __shfl_down(s,  off, 64);
        s2 += __shfl_down(s2, off, 64);
    }
    __shared__ float sh[4], sh2[4];
    int wave = t >> 6;
    if ((t & 63) == 0) { sh[wave] = s; sh2[wave] = s2; }
    __syncthreads();
    if (t == 0) {
        float ts = 0.f, ts2 = 0.f;
        for (int w = 0; w < 4; ++w) { ts += sh[w]; ts2 += sh2[w]; }
        const float invN = 1.f / (float)(BB * HWN);
        float m = ts * invN;
        float var = ts2 * invN - m * m;
        mean[c] = m;
        rstd[c] = rsqrtf(var + 1e-5f);
    }
}

// ------- BN apply + transpose: x[b][c][s] -> outT[b][s][c] bf16 (+relu) -------
template <bool RELU, bool INBF16>
__global__ __launch_bounds__(256) void bn_apply_t_kernel(const void* __restrict__ xv,
                                                         const float* __restrict__ mean,
                                                         const float* __restrict__ rstd,
                                                         const float* __restrict__ g,
                                                         const float* __restrict__ bta,
                                                         unsigned short* __restrict__ outT) {
    __shared__ float tile[64][65];
    int b  = blockIdx.z;
    int c0 = blockIdx.y * 64;
    int s0 = blockIdx.x * 64;
    int t = threadIdx.x;
    int sl = t & 63, grp = t >> 6;
#pragma unroll
    for (int i = 0; i < 16; ++i) {
        int cr = i * 4 + grp;
        int c = c0 + cr;
        float r  = rstd[c] * g[c];
        float sh = bta[c] - mean[c] * r;
        float xval;
        if (INBF16) {
            const unsigned short* xb = (const unsigned short*)xv;
            xval = bf2f(xb[((size_t)b * CC + c0 + cr) * HWN + s0 + sl]);
        } else {
            const float* xb = (const float*)xv;
            xval = xb[((size_t)b * CC + c0 + cr) * HWN + s0 + sl];
        }
        float v = fmaf(xval, r, sh);
        if (RELU) v = fmaxf(v, 0.f);
        tile[cr][sl] = v;
    }
    __syncthreads();
    unsigned short* ob = outT + ((size_t)b * HWN + s0) * CC + c0;
#pragma unroll
    for (int i = 0; i < 16; ++i) {
        int srow = i * 4 + grp;
        ob[(size_t)srow * CC + sl] = f2bf(tile[sl][srow]);
    }
}

// -------- reduce: bn2 mean/rstd from per-block partial (sum, sumsq) pairs ------
// part layout: [pair p = b*8+n][2][512] -> p*1024 + {0,512} + c
__global__ __launch_bounds__(256) void reduce_bnstats_kernel(const float* __restrict__ part,
                                                             float* __restrict__ mean,
                                                             float* __restrict__ rstd) {
    int c = blockIdx.x * 256 + threadIdx.x;  // 512
    float s = 0.f, s2 = 0.f;
    for (int p = 0; p < BB * 8; ++p) {
        s  += part[(size_t)p * 1024 + c];
        s2 += part[(size_t)p * 1024 + 512 + c];
    }
    const float invN = 1.f / (float)(BB * HWN);
    float m = s * invN;
    mean[c] = m;
    rstd[c] = rsqrtf(s2 * invN - m * m + 1e-5f);
}

// ---------------- Fused attention core: steps 4+5+6 in one kernel -------------
// Per block: 256 c-rows (half) x 128 k-tokens; loop q in chunks of 64.
// VMEM ISSUE ORDER inside each iter is the whole point (vmcnt is a FIFO):
//   1) Q[i] fragment loads to REGISTERS (issued FIRST -> oldest)
//   2) V[i+1] global_load_lds (16 ops, stay in flight)
//   3) E-phase MFMAs consume Q -> compiler waits vmcnt(16): only Q drained,
//      V flies across E+exp+barrier1+PV until the end-of-iter __syncthreads.
// (Round-4 had Q issued AFTER V -> consuming Q implied vmcnt(0) -> force-drained
//  the 32 KB V stage with no cover; that was the 72->98 us regression.)
// barrier1 (Es visibility) is LDS-only: s_waitcnt lgkmcnt(0) + raw s_barrier.
// Epilogue: acc * (1/S[k]) + x (fp32), bf16 store to xr, fused bn2 partials
//           (scratch overlaid on Es -> LDS exactly 80 KB -> 2 blocks/CU).
// 512 blocks, remapped so all 16 blocks of batch bb share an XCD.
__global__ __launch_bounds__(512, 4) void fused_pv_kernel(
        const unsigned short* __restrict__ qkTg,  // [b][1024][128] (q d 0..63, k d 64..127)
        const unsigned short* __restrict__ vg,    // [b][512][1024]
        const float* __restrict__ xg,             // [b][512][1024] fp32 resid
        unsigned short* __restrict__ xrg,         // [b][512][1024] bf16 out
        float* __restrict__ rowpart) {            // [b*8+nb][2][512] bn2 partials
    __shared__ __align__(16) unsigned short Vs[2][2 * 256 * 32];  // 64 KB dbuf
    __shared__ __align__(16) unsigned short Es[2 * 128 * 32];     // 16 KB (+ epilogue overlay)
    float* sS  = (float*)Es;               // [128]    (valid after loop)
    float* rsS = (float*)Es + 128;         // [2][256]
    float* rqS = (float*)Es + 128 + 512;   // [2][256]

    int lin = blockIdx.x + 16 * blockIdx.z;  // dispatch-linear (x fastest)
    int b  = lin & 31;                       // XCD = lin % 8 = b % 8 (heuristic)
    int nn = (lin >> 5) & 7;
    int ch = lin >> 8;
    int n0 = nn * 128;
    int c0 = ch * 256;
    const unsigned short* qk = qkTg + (size_t)b * (HWN * 128);
    const unsigned short* vb = vg + (size_t)b * ((size_t)CC * HWN);
    int t = threadIdx.x;
    int wv = t >> 6, L = t & 63;
    int lr = L & 15, lq = L >> 4;
    int swz = (lr >> 1) & 3;
    int cstrip = (wv >> 1) * 64;
    int khalf = (wv & 1) * 64;

    // K fragments -> registers (wave-private rows n0+wv*16+lr, reused 16 iters)
    bf16x8 kfr[2];
#pragma unroll
    for (int kkd = 0; kkd < 2; ++kkd)
        kfr[kkd] = *(const bf16x8*)(qk + (size_t)(n0 + wv * 16 + lr) * 128 + 64 + kkd * 32 + lq * 8);

    // prologue: stage V chunk 0 -> Vs[0]
#pragma unroll
    for (int is = 0; is < 4; ++is) {
        int idx = is * 512 + t;
        int kkq = idx >> 10, row = (idx >> 2) & 255, slot = idx & 3;
        int chk = slot ^ ((row >> 1) & 3);
        gload_lds16(vb + (size_t)(c0 + row) * HWN + kkq * 32 + chk * 8, &Vs[0][idx * 8]);
    }
    __syncthreads();  // V0 landed

    f32x4 acc[4][4] = {};
    float S = 0.f;
    int p = 0;
    for (int i = 0; i < 16; ++i) {
        int q0 = i * 64;

        // ---- (1) Q[i] fragments -> registers, issued FIRST (oldest VMEM) ----
        bf16x8 qa[2][4];
#pragma unroll
        for (int kkd = 0; kkd < 2; ++kkd)
#pragma unroll
            for (int qi = 0; qi < 4; ++qi)
                qa[kkd][qi] = *(const bf16x8*)(qk + (size_t)(q0 + qi * 16 + lr) * 128 + kkd * 32 + lq * 8);
        __builtin_amdgcn_sched_barrier(0);  // pin: Q issues before V staging

        // ---- (2) stage V chunk i+1 -> Vs[p^1]; in flight until end-of-iter ----
        if (i + 1 < 16) {
#pragma unroll
            for (int is = 0; is < 4; ++is) {
                int idx = is * 512 + t;
                int kkq = idx >> 10, row = (idx >> 2) & 255, slot = idx & 3;
                int chk = slot ^ ((row >> 1) & 3);
                gload_lds16(vb + (size_t)(c0 + row) * HWN + q0 + 64 + kkq * 32 + chk * 8,
                            &Vs[p ^ 1][idx * 8]);
            }
        }
        __builtin_amdgcn_sched_barrier(0);  // pin: V staging issued before E-phase waits

        // ---- (3) E-phase: q 0..63 x k [wv*16,+16); waits vmcnt(16) (Q only) ----
        f32x4 eacc[4] = {};
#pragma unroll
        for (int kkd = 0; kkd < 2; ++kkd)
#pragma unroll
            for (int qi = 0; qi < 4; ++qi)
                eacc[qi] = __builtin_amdgcn_mfma_f32_16x16x32_bf16(qa[kkd][qi], kfr[kkd], eacc[qi], 0, 0, 0);
        // exp + pack to Es[k][q] (lane holds 4 q-contig values for k=wv*16+lr)
        float spart = 0.f;
#pragma unroll
        for (int qi = 0; qi < 4; ++qi) {
            float e0 = __expf(eacc[qi][0] * 0.125f);
            float e1 = __expf(eacc[qi][1] * 0.125f);
            float e2 = __expf(eacc[qi][2] * 0.125f);
            float e3 = __expf(eacc[qi][3] * 0.125f);
            spart += (e0 + e1) + (e2 + e3);
            unsigned int lo = (unsigned int)f2bf(e0) | ((unsigned int)f2bf(e1) << 16);
            unsigned int hi = (unsigned int)f2bf(e2) | ((unsigned int)f2bf(e3) << 16);
            int kkq = qi >> 1;
            int chunkE = (qi & 1) * 2 + (lq >> 1);
            int addr = kkq * 4096 + (wv * 16 + lr) * 32 + ((chunkE ^ swz) * 8) + (lq & 1) * 4;
            *(uint2*)&Es[addr] = make_uint2(lo, hi);
        }
        spart += __shfl_xor(spart, 16, 64);
        spart += __shfl_xor(spart, 32, 64);  // full sum over this wave's 64 q
        S += spart;

        // barrier1: LDS-only (Es visibility). NO vmcnt drain -> V keeps flying.
        __builtin_amdgcn_sched_barrier(0);
        asm volatile("s_waitcnt lgkmcnt(0)" ::: "memory");
        __builtin_amdgcn_s_barrier();
        __builtin_amdgcn_sched_barrier(0);

        // ---- PV-phase: acc[c][k] += v[c][q] * Es[k][q], 2 K-steps of 32 ----
#pragma unroll
        for (int kk = 0; kk < 2; ++kk) {
            bf16x8 af[4], bfj[4];
#pragma unroll
            for (int ii = 0; ii < 4; ++ii)
                af[ii] = *(const bf16x8*)&Vs[p][kk * 8192 + (cstrip + ii * 16 + lr) * 32 + ((lq ^ swz) * 8)];
#pragma unroll
            for (int j = 0; j < 4; ++j)
                bfj[j] = *(const bf16x8*)&Es[kk * 4096 + (khalf + j * 16 + lr) * 32 + ((lq ^ swz) * 8)];
#pragma unroll
            for (int ii = 0; ii < 4; ++ii)
#pragma unroll
                for (int j = 0; j < 4; ++j)
                    acc[ii][j] = __builtin_amdgcn_mfma_f32_16x16x32_bf16(af[ii], bfj[j], acc[ii][j], 0, 0, 0);
        }
        __syncthreads();  // barrier2: vmcnt+lgkm drain; V[i+1] landed; Es/Vs[p] free
        p ^= 1;
    }

    // softmax denominators -> LDS broadcast (overlay on Es; loop closed by barrier2)
    if (lq == 0) sS[wv * 16 + lr] = S;
    __syncthreads();
    float inv[4];
#pragma unroll
    for (int j = 0; j < 4; ++j) inv[j] = 1.f / sS[khalf + j * 16 + lr];

    const float* xb = xg + (size_t)b * ((size_t)CC * HWN);
    unsigned short* xrb = xrg + (size_t)b * ((size_t)CC * HWN);
#pragma unroll
    for (int ii = 0; ii < 4; ++ii) {
#pragma unroll
        for (int r = 0; r < 4; ++r) {
            int rloc = cstrip + ii * 16 + lq * 4 + r;   // 0..255
            int row = c0 + rloc;
            float s = 0.f, q2 = 0.f;
#pragma unroll
            for (int j = 0; j < 4; ++j) {
                int col = n0 + khalf + j * 16 + lr;
                float val = acc[ii][j][r] * inv[j];
                size_t off = (size_t)row * HWN + col;
                val += xb[off];
                s += val; q2 += val * val;
                xrb[off] = f2bf(val);
            }
#pragma unroll
            for (int m = 1; m <= 8; m <<= 1) {
                s += __shfl_xor(s, m, 64);
                q2 += __shfl_xor(q2, m, 64);
            }
            if (lr == 0) { rsS[(wv & 1) * 256 + rloc] = s; rqS[(wv & 1) * 256 + rloc] = q2; }
        }
    }
    __syncthreads();
    {
        size_t base = ((size_t)b * 8 + nn) * 1024;
        int rloc = t & 255;
        if (t < 256) rowpart[base + c0 + rloc]       = rsS[rloc] + rsS[256 + rloc];
        else         rowpart[base + 512 + c0 + rloc] = rqS[rloc] + rqS[256 + rloc];
    }
}

// ---------------- MFMA bf16 GEMM: C[b] = scale*(A @ Bt^T) (+bias)(+relu)(+resid)
template <bool OUTBF16, int BIASMODE /*0 none,1 row,2 col*/, bool RELU,
          int RESMODE /*0,1=f32,2=bf16*/>
__global__ __launch_bounds__(256, 4) void mfma_gemm(const unsigned short* __restrict__ A,
                                                 const unsigned short* __restrict__ Bt,
                                                 const float* __restrict__ bias,
                                                 const void* __restrict__ resid,
                                                 void* __restrict__ C,
                                                 int K, int lda, int ldb, int ldc,
                                                 long strideA, long strideB, long strideC,
                                                 float scale) {
    __shared__ __align__(16) unsigned short As[2][128 * 32];
    __shared__ __align__(16) unsigned short Bs[2][128 * 32];
    int b  = blockIdx.z;
    int m0 = blockIdx.y * 128;
    int n0 = blockIdx.x * 128;
    const unsigned short* Ab = A  + (size_t)b * strideA;
    const unsigned short* Bb = Bt + (size_t)b * strideB;
    int t = threadIdx.x;
    int wv = t >> 6, L = t & 63;
    int wm = (wv >> 1) * 64, wn = (wv & 1) * 64;
    int lr = L & 15, lq = L >> 4;
    int srow = t >> 2;                       // staged row 0..63 (per half)
    int gchunk = (t & 3) ^ ((t >> 3) & 3);   // global 16B chunk, swizzle-matched
    int skof = gchunk * 8;                   // bf16 elem offset in k
    int swz = (lr >> 1) & 3;                 // read-side swizzle

    int aoff[4], boff[4];
#pragma unroll
    for (int i = 0; i < 4; ++i) {
        aoff[i] = (wm + i * 16 + lr) * 32 + ((lq ^ swz) * 8);
        boff[i] = (wn + i * 16 + lr) * 32 + ((lq ^ swz) * 8);
    }

    const unsigned short* gA0 = Ab + (size_t)(m0 + srow) * lda + skof;
    const unsigned short* gA1 = Ab + (size_t)(m0 + 64 + srow) * lda + skof;
    const unsigned short* gB0 = Bb + (size_t)(n0 + srow) * ldb + skof;
    const unsigned short* gB1 = Bb + (size_t)(n0 + 64 + srow) * ldb + skof;

    f32x4 acc[4][4] = {};
    int nIter = K >> 5;

    gload_lds16(gA0, &As[0][t * 8]);
    gload_lds16(gA1, &As[0][64 * 32 + t * 8]);
    gload_lds16(gB0, &Bs[0][t * 8]);
    gload_lds16(gB1, &Bs[0][64 * 32 + t * 8]);

    int p = 0;
    for (int i = 0; i < nIter; ++i) {
        __syncthreads();
        if (i + 1 < nIter) {
            int ko = (i + 1) << 5;
            gload_lds16(gA0 + ko, &As[p ^ 1][t * 8]);
            gload_lds16(gA1 + ko, &As[p ^ 1][64 * 32 + t * 8]);
            gload_lds16(gB0 + ko, &Bs[p ^ 1][t * 8]);
            gload_lds16(gB1 + ko, &Bs[p ^ 1][64 * 32 + t * 8]);
        }
        bf16x8 af[4], bfr[4];
#pragma unroll
        for (int j = 0; j < 4; ++j) af[j]  = *(const bf16x8*)&As[p][aoff[j]];
#pragma unroll
        for (int j = 0; j < 4; ++j) bfr[j] = *(const bf16x8*)&Bs[p][boff[j]];
#pragma unroll
        for (int ii = 0; ii < 4; ++ii)
#pragma unroll
            for (int jj = 0; jj < 4; ++jj)
                acc[ii][jj] = __builtin_amdgcn_mfma_f32_16x16x32_bf16(af[ii], bfr[jj], acc[ii][jj], 0, 0, 0);
        p ^= 1;
    }

    // epilogue: lane L, reg r -> row = lq*4 + r, col = lr (within 16x16 tile)
#pragma unroll
    for (int i = 0; i < 4; ++i) {
#pragma unroll
        for (int r = 0; r < 4; ++r) {
            int row = m0 + wm + i * 16 + lq * 4 + r;
            float brow = (BIASMODE == 1) ? bias[row] : 0.f;
#pragma unroll
            for (int j = 0; j < 4; ++j) {
                int col = n0 + wn + j * 16 + lr;
                float v = acc[i][j][r] * scale;
                if (BIASMODE == 1) v += brow;
                if (BIASMODE == 2) v += bias[col];
                if (RELU) v = fmaxf(v, 0.f);
                size_t off = (size_t)b * strideC + (size_t)row * ldc + col;
                if (RESMODE == 1) v += ((const float*)resid)[off];
                if (RESMODE == 2) v += bf2f(((const unsigned short*)resid)[off]);
                if (OUTBF16) ((unsigned short*)C)[off] = f2bf(v);
                else         ((float*)C)[off] = v;
            }
        }
    }
}

extern "C" void kernel_launch(void* const* d_in, const int* in_sizes, int n_in,
                              void* d_out, int out_size, void* d_ws, size_t ws_size,
                              hipStream_t stream) {
    const float* x     = (const float*)d_in[0];
    const float* bn1_g = (const float*)d_in[1];
    const float* bn1_b = (const float*)d_in[2];
    const float* W_qkv = (const float*)d_in[3];
    const float* b_qkv = (const float*)d_in[4];
    const float* bn2_g = (const float*)d_in[5];
    const float* bn2_b = (const float*)d_in[6];
    const float* W1    = (const float*)d_in[7];
    const float* b1    = (const float*)d_in[8];
    const float* W2    = (const float*)d_in[9];
    const float* b2    = (const float*)d_in[10];
    float* out = (float*)d_out;
    char* ws = (char*)d_ws;

    // workspace layout (bytes):
    unsigned short* hT    = (unsigned short*)(ws);                 // 32 MB (hT -> ybnT)
    unsigned short* qkT   = (unsigned short*)(ws + 33554432);      // 8 MB
    unsigned short* v     = (unsigned short*)(ws + 41943040);      // 32 MB (v -> y1T)
    unsigned short* xr    = (unsigned short*)(ws + 142606336);     // 32 MB (bf16 xr)
    unsigned short* Wqkvb = (unsigned short*)(ws + 176160768);     // 640 KB
    unsigned short* W1b   = (unsigned short*)(ws + 176816128);     // 512 KB
    unsigned short* W2b   = (unsigned short*)(ws + 177340416);     // 512 KB
    float* stats = (float*)(ws + 177864704);                       // 2048 f32
    float* mean1 = stats,        *rstd1 = stats + 512;
    float* mean2 = stats + 1024, *rstd2 = stats + 1536;
    unsigned short* ybnT = hT;
    unsigned short* y1T  = v;
    // scratch aliased into hT region (hT dead between step 3b and step 8):
    float* rowpartBN = (float*)(ws + 1179648);   // [32*8][2][512] = 1 MB

    const long sHT = (long)HWN * CC;    // 1024*512
    const long sQK = (long)HWN * 128;   // 1024*128
    const long sV  = (long)CC * HWN;    // 512*1024

    // 0. weights -> bf16 (single launch)
    cvt3_kernel<<<(OO * CC + 2 * CC * CC) / 256, 256, 0, stream>>>(W_qkv, W1, W2, Wqkvb, W1b, W2b);
    // 1. bn1 stats (fp32 x)
    bn_stats_kernel<false><<<CC, 256, 0, stream>>>(x, mean1, rstd1);
    // 2. hT[b][s][c] = relu(bn1(x)) transposed, bf16
    bn_apply_t_kernel<true, false><<<dim3(16, 8, BB), 256, 0, stream>>>(x, mean1, rstd1, bn1_g, bn1_b, hT);
    // 3a. qkT[s][o'] = hT @ Wqk^T + b_qkv[o']   (M=1024, N=128, K=512), col bias
    mfma_gemm<true, 2, false, 0><<<dim3(1, 8, BB), 256, 0, stream>>>(
        hT, Wqkvb, b_qkv, nullptr, qkT, 512, 512, 512, 128, sHT, 0, sQK, 1.f);
    // 3b. v[c][s] = Wv @ h + b_qkv[128+c]       (M=512, N=1024, K=512), row bias
    mfma_gemm<true, 1, false, 0><<<dim3(8, 4, BB), 256, 0, stream>>>(
        Wqkvb + 128 * 512, hT, b_qkv + 128, nullptr, v, 512, 512, 512, 1024, 0, sHT, sV, 1.f);
    // 4-6. fused: E = exp(QK^T/8) on the fly, denom in-register, PV + x resid,
    //      bf16 xr out, fused bn2 partials; Q-first vmcnt ordering, V dbuf,
    //      LDS-only barrier1
    fused_pv_kernel<<<dim3(16, 1, BB), 512, 0, stream>>>(qkT, v, x, xr, rowpartBN);
    // 7. bn2 stats from fused partials
    reduce_bnstats_kernel<<<2, 256, 0, stream>>>(rowpartBN, mean2, rstd2);
    // 8. ybnT[s][c] = bn2(xr) transposed, bf16 (aliases hT)
    bn_apply_t_kernel<false, true><<<dim3(16, 8, BB), 256, 0, stream>>>(xr, mean2, rstd2, bn2_g, bn2_b, ybnT);
    // 9. y1T[s][o] = relu(ybnT @ W1^T + b1)     (M=1024, N=512, K=512), col bias (aliases v)
    mfma_gemm<true, 2, true, 0><<<dim3(4, 8, BB), 256, 0, stream>>>(
        ybnT, W1b, b1, nullptr, y1T, 512, 512, 512, 512, sHT, 0, sHT, 1.f);
    // 10. out[c][s] = W2 @ y1T^T + b2 + xr(bf16) -> d_out fp32  (M=512, N=1024, K=512)
    mfma_gemm<false, 1, false, 2><<<dim3(8, 4, BB), 256, 0, stream>>>(
        W2b, y1T, b2, xr, out, 512, 512, 512, 1024, 0, sHT, sV, 1.f);
}

// Round 8
// 329.860 us; speedup vs baseline: 1.2336x; 1.2336x over previous
//
#include <hip/hip_runtime.h>

#define BB 32
#define CC 512
#define HWN 1024
#define DD 64
#define OO 640  // 2*DD + CC

typedef short bf16x8 __attribute__((ext_vector_type(8)));
typedef float f32x4 __attribute__((ext_vector_type(4)));
typedef __attribute__((address_space(1))) const void gvoid;
typedef __attribute__((address_space(3))) void svoid;

__device__ __forceinline__ void gload_lds16(const void* g, void* l) {
    __builtin_amdgcn_global_load_lds((gvoid*)g, (svoid*)l, 16, 0, 0);
}

__device__ __forceinline__ unsigned short f2bf(float f) {
    unsigned int u = __float_as_uint(f);
    unsigned int r = u + 0x7FFFu + ((u >> 16) & 1u);  // RNE
    return (unsigned short)(r >> 16);
}
__device__ __forceinline__ float bf2f(unsigned short h) {
    return __uint_as_float(((unsigned int)h) << 16);
}

// ---------------- f32 -> bf16 convert, all 3 weight matrices in one launch ----
__global__ __launch_bounds__(256) void cvt3_kernel(const float* __restrict__ a,
                                                   const float* __restrict__ b,
                                                   const float* __restrict__ c,
                                                   unsigned short* __restrict__ oa,
                                                   unsigned short* __restrict__ ob,
                                                   unsigned short* __restrict__ oc) {
    const int n1 = OO * CC, n2 = CC * CC;
    int i = blockIdx.x * 256 + threadIdx.x;
    if (i < n1)            oa[i] = f2bf(a[i]);
    else if (i < n1 + n2)  ob[i - n1] = f2bf(b[i - n1]);
    else                   oc[i - n1 - n2] = f2bf(c[i - n1 - n2]);
}

// ---------------- BN stats: one block per channel (fp32 input, bn1 only) ------
// f32 path vectorized to float4 (16 B/lane, G13).
template <bool INBF16>
__global__ __launch_bounds__(256) void bn_stats_kernel(const void* __restrict__ xv,
                                                       float* __restrict__ mean,
                                                       float* __restrict__ rstd) {
    int c = blockIdx.x;
    int t = threadIdx.x;
    float s = 0.f, s2 = 0.f;
    if (INBF16) {
        const unsigned int* x = (const unsigned int*)xv;  // 2 bf16 per uint
        for (int b = 0; b < BB; ++b) {
            const unsigned int* p = x + ((size_t)b * CC + c) * (HWN / 2);
#pragma unroll
            for (int i = 0; i < 2; ++i) {
                unsigned int w = p[t + i * 256];
                float v0 = bf2f((unsigned short)(w & 0xffffu));
                float v1 = bf2f((unsigned short)(w >> 16));
                s += v0 + v1; s2 += v0 * v0 + v1 * v1;
            }
        }
    } else {
        const float* x = (const float*)xv;
        for (int b = 0; b < BB; ++b) {
            const float* p = x + ((size_t)b * CC + c) * HWN;
            float4 f = *(const float4*)&p[t * 4];
            s += (f.x + f.y) + (f.z + f.w);
            s2 += (f.x * f.x + f.y * f.y) + (f.z * f.z + f.w * f.w);
        }
    }
    for (int off = 32; off > 0; off >>= 1) {
        s  += __shfl_down(s,  off, 64);
        s2 += __shfl_down(s2, off, 64);
    }
    __shared__ float sh[4], sh2[4];
    int wave = t >> 6;
    if ((t & 63) == 0) { sh[wave] = s; sh2[wave] = s2; }
    __syncthreads();
    if (t == 0) {
        float ts = 0.f, ts2 = 0.f;
        for (int w = 0; w < 4; ++w) { ts += sh[w]; ts2 += sh2[w]; }
        const float invN = 1.f / (float)(BB * HWN);
        float m = ts * invN;
        float var = ts2 * invN - m * m;
        mean[c] = m;
        rstd[c] = rsqrtf(var + 1e-5f);
    }
}

// ------- BN apply + transpose: x[b][c][s] -> outT[b][s][c] bf16 (+relu) -------
// Vectorized: float4/ushort4 loads (16/8 B per lane), ushort4 stores (8 B/lane).
// tile[64][65] padding: store-phase lane stride = 4*65 floats -> bank stride 4
// -> 2 lanes/bank (free).
template <bool RELU, bool INBF16>
__global__ __launch_bounds__(256) void bn_apply_t_kernel(const void* __restrict__ xv,
                                                         const float* __restrict__ mean,
                                                         const float* __restrict__ rstd,
                                                         const float* __restrict__ g,
                                                         const float* __restrict__ bta,
                                                         unsigned short* __restrict__ outT) {
    __shared__ float tile[64][65];
    int b  = blockIdx.z;
    int c0 = blockIdx.y * 64;
    int s0 = blockIdx.x * 64;
    int t = threadIdx.x;
    int lane16 = t & 15, grp16 = t >> 4;  // 16 lanes x 16 groups
#pragma unroll
    for (int p = 0; p < 4; ++p) {
        int cr = p * 16 + grp16;          // c-row within tile
        int c = c0 + cr;
        float r  = rstd[c] * g[c];
        float sh = bta[c] - mean[c] * r;
        int col = lane16 * 4;             // s-col within tile
        float v0, v1, v2, v3;
        if (INBF16) {
            const unsigned short* xb = (const unsigned short*)xv;
            ushort4 w = *(const ushort4*)&xb[((size_t)b * CC + c) * HWN + s0 + col];
            v0 = bf2f(w.x); v1 = bf2f(w.y); v2 = bf2f(w.z); v3 = bf2f(w.w);
        } else {
            const float* xb = (const float*)xv;
            float4 f = *(const float4*)&xb[((size_t)b * CC + c) * HWN + s0 + col];
            v0 = f.x; v1 = f.y; v2 = f.z; v3 = f.w;
        }
        v0 = fmaf(v0, r, sh); v1 = fmaf(v1, r, sh);
        v2 = fmaf(v2, r, sh); v3 = fmaf(v3, r, sh);
        if (RELU) {
            v0 = fmaxf(v0, 0.f); v1 = fmaxf(v1, 0.f);
            v2 = fmaxf(v2, 0.f); v3 = fmaxf(v3, 0.f);
        }
        tile[cr][col + 0] = v0; tile[cr][col + 1] = v1;
        tile[cr][col + 2] = v2; tile[cr][col + 3] = v3;
    }
    __syncthreads();
    unsigned short* ob = outT + ((size_t)b * HWN + s0) * CC + c0;
#pragma unroll
    for (int p = 0; p < 4; ++p) {
        int srow = p * 16 + grp16;        // s-row of output
        int c4 = lane16 * 4;              // c-col of output
        ushort4 o;
        o.x = f2bf(tile[c4 + 0][srow]);
        o.y = f2bf(tile[c4 + 1][srow]);
        o.z = f2bf(tile[c4 + 2][srow]);
        o.w = f2bf(tile[c4 + 3][srow]);
        *(ushort4*)&ob[(size_t)srow * CC + c4] = o;
    }
}

// -------- reduce: bn2 mean/rstd from per-block partial (sum, sumsq) pairs ------
// part layout: [pair p = b*8+n][2][512] -> p*1024 + {0,512} + c
__global__ __launch_bounds__(256) void reduce_bnstats_kernel(const float* __restrict__ part,
                                                             float* __restrict__ mean,
                                                             float* __restrict__ rstd) {
    int c = blockIdx.x * 256 + threadIdx.x;  // 512
    float s = 0.f, s2 = 0.f;
    for (int p = 0; p < BB * 8; ++p) {
        s  += part[(size_t)p * 1024 + c];
        s2 += part[(size_t)p * 1024 + 512 + c];
    }
    const float invN = 1.f / (float)(BB * HWN);
    float m = s * invN;
    mean[c] = m;
    rstd[c] = rsqrtf(s2 * invN - m * m + 1e-5f);
}

// ---------------- Fused attention core: steps 4+5+6 in one kernel -------------
// (Round-3 structure: measured 72 us. The K-in-regs / direct-Q restructures of
//  rounds 4-5 regressed to 98/119 us.)
// Per block: 256 c-rows (half) x 128 k-tokens; loop q in chunks of 64.
//   E-phase: beta[q,k] = (Q @ K^T)/8 via MFMA, E = exp(beta) -> bf16 -> Es LDS
//            (PV B-operand layout [k][q]); f32 row-sums accumulate denom S[k].
//   PV-phase: acc[c][k] += v[c][q] * Es[k][q].
// Epilogue: acc * (1/S[k]) + x (fp32), bf16 store to xr, fused bn2 partials.
// 512 blocks (16 x 32 grid), remapped so all 16 blocks of batch bb share an XCD
// (linear id = bb mod 32 => id mod 8 = bb mod 8) -> v[bb] chunk stays L2-hot.
// 512 thr = 8 waves: [wv>>1]=c-strip of 64, [wv&1]=k-half of 64.
// LDS 76.5 KB -> 2 blocks/CU.
__global__ __launch_bounds__(512, 4) void fused_pv_kernel(
        const unsigned short* __restrict__ qkTg,  // [b][1024][128] (q dims 0..63, k dims 64..127)
        const unsigned short* __restrict__ vg,    // [b][512][1024]
        const float* __restrict__ xg,             // [b][512][1024] fp32 resid
        unsigned short* __restrict__ xrg,         // [b][512][1024] bf16 out
        float* __restrict__ rowpart) {            // [b*8+nb][2][512] bn2 partials
    __shared__ __align__(16) unsigned short Ks[2 * 128 * 32];   // [kkd][k][32]
    __shared__ __align__(16) unsigned short Qs[2 * 64 * 32];    // [kkd][q][32] single-buf
    __shared__ __align__(16) unsigned short Vs[2 * 256 * 32];   // [kkq][c][32]
    __shared__ __align__(16) unsigned short Es[2 * 128 * 32];   // [kkq][k][32]
    __shared__ float sS[128];
    __shared__ float rsS[2][256];
    __shared__ float rqS[2][256];

    int lin = blockIdx.x + 16 * blockIdx.z;  // dispatch-linear (x fastest)
    int b  = lin & 31;                       // XCD = lin % 8 = b % 8 (heuristic)
    int nn = (lin >> 5) & 7;
    int ch = lin >> 8;
    int n0 = nn * 128;
    int c0 = ch * 256;
    const unsigned short* qk = qkTg + (size_t)b * (HWN * 128);
    const unsigned short* vb = vg + (size_t)b * ((size_t)CC * HWN);
    int t = threadIdx.x;
    int wv = t >> 6, L = t & 63;
    int lr = L & 15, lq = L >> 4;
    int swz = (lr >> 1) & 3;
    int cstrip = (wv >> 1) * 64;
    int khalf = (wv & 1) * 64;

    // prologue staging: K tile (1024 chunks) + Q chunk 0 (512 chunks)
#pragma unroll
    for (int is = 0; is < 2; ++is) {
        int idx = is * 512 + t;
        int kkd = idx >> 9, row = (idx >> 2) & 127, slot = idx & 3;
        int chk = slot ^ ((row >> 1) & 3);
        gload_lds16(qk + (size_t)(n0 + row) * 128 + 64 + kkd * 32 + chk * 8, &Ks[idx * 8]);
    }
    {
        int kkd = t >> 8, row = (t >> 2) & 63, slot = t & 3;
        int chk = slot ^ ((row >> 1) & 3);
        gload_lds16(qk + (size_t)row * 128 + kkd * 32 + chk * 8, &Qs[t * 8]);
    }

    f32x4 acc[4][4] = {};
    float S = 0.f;
    for (int i = 0; i < 16; ++i) {
        int q0 = i * 64;
        // stage V chunk i (rows c0..c0+255, q0..q0+63); covered by E-phase
#pragma unroll
        for (int is = 0; is < 4; ++is) {
            int idx = is * 512 + t;
            int kkq = idx >> 10, row = (idx >> 2) & 255, slot = idx & 3;
            int chk = slot ^ ((row >> 1) & 3);
            gload_lds16(vb + (size_t)(c0 + row) * HWN + q0 + kkq * 32 + chk * 8, &Vs[idx * 8]);
        }
        if (i == 0) __syncthreads();  // drain K, Q0, V0 (iter-0 only)

        // ---- E-phase: each wave computes q 0..63 x k [wv*16, wv*16+16) ----
        f32x4 eacc[4] = {};
#pragma unroll
        for (int kkd = 0; kkd < 2; ++kkd) {
            bf16x8 kb = *(const bf16x8*)&Ks[kkd * 4096 + (wv * 16 + lr) * 32 + ((lq ^ swz) * 8)];
#pragma unroll
            for (int qi = 0; qi < 4; ++qi) {
                bf16x8 qa = *(const bf16x8*)&Qs[kkd * 2048 + (qi * 16 + lr) * 32 + ((lq ^ swz) * 8)];
                eacc[qi] = __builtin_amdgcn_mfma_f32_16x16x32_bf16(qa, kb, eacc[qi], 0, 0, 0);
            }
        }
        // exp + pack to Es[k][q] (lane holds 4 q-contig values for k=wv*16+lr)
        float spart = 0.f;
#pragma unroll
        for (int qi = 0; qi < 4; ++qi) {
            float e0 = __expf(eacc[qi][0] * 0.125f);
            float e1 = __expf(eacc[qi][1] * 0.125f);
            float e2 = __expf(eacc[qi][2] * 0.125f);
            float e3 = __expf(eacc[qi][3] * 0.125f);
            spart += (e0 + e1) + (e2 + e3);
            unsigned int lo = (unsigned int)f2bf(e0) | ((unsigned int)f2bf(e1) << 16);
            unsigned int hi = (unsigned int)f2bf(e2) | ((unsigned int)f2bf(e3) << 16);
            int kkq = qi >> 1;
            int chunkE = (qi & 1) * 2 + (lq >> 1);
            int addr = kkq * 4096 + (wv * 16 + lr) * 32 + ((chunkE ^ swz) * 8) + (lq & 1) * 4;
            *(uint2*)&Es[addr] = make_uint2(lo, hi);
        }
        spart += __shfl_xor(spart, 16, 64);
        spart += __shfl_xor(spart, 32, 64);  // full sum over this wave's 64 q
        S += spart;
        __syncthreads();  // barrier1: Es visible; V[i] drained (vmcnt0)

        // stage Q chunk i+1 (single buffer: all waves done reading Qs for
        // iter i; drained by barrier2 under cover of PV MFMAs)
        if (i + 1 < 16) {
            int kkd = t >> 8, row = (t >> 2) & 63, slot = t & 3;
            int chk = slot ^ ((row >> 1) & 3);
            gload_lds16(qk + (size_t)(q0 + 64 + row) * 128 + kkd * 32 + chk * 8, &Qs[t * 8]);
        }

        // ---- PV-phase: acc[c][k] += v[c][q] * Es[k][q], 2 K-steps of 32 ----
#pragma unroll
        for (int kk = 0; kk < 2; ++kk) {
            bf16x8 af[4], bfj[4];
#pragma unroll
            for (int ii = 0; ii < 4; ++ii)
                af[ii] = *(const bf16x8*)&Vs[kk * 8192 + (cstrip + ii * 16 + lr) * 32 + ((lq ^ swz) * 8)];
#pragma unroll
            for (int j = 0; j < 4; ++j)
                bfj[j] = *(const bf16x8*)&Es[kk * 4096 + (khalf + j * 16 + lr) * 32 + ((lq ^ swz) * 8)];
#pragma unroll
            for (int ii = 0; ii < 4; ++ii)
#pragma unroll
                for (int j = 0; j < 4; ++j)
                    acc[ii][j] = __builtin_amdgcn_mfma_f32_16x16x32_bf16(af[ii], bfj[j], acc[ii][j], 0, 0, 0);
        }
        __syncthreads();  // barrier2: Es/Vs free; Q[i+1] drained
    }

    // softmax denominators -> LDS broadcast
    if (lq == 0) sS[wv * 16 + lr] = S;
    __syncthreads();
    float inv[4];
#pragma unroll
    for (int j = 0; j < 4; ++j) inv[j] = 1.f / sS[khalf + j * 16 + lr];

    const float* xb = xg + (size_t)b * ((size_t)CC * HWN);
    unsigned short* xrb = xrg + (size_t)b * ((size_t)CC * HWN);
#pragma unroll
    for (int ii = 0; ii < 4; ++ii) {
#pragma unroll
        for (int r = 0; r < 4; ++r) {
            int rloc = cstrip + ii * 16 + lq * 4 + r;   // 0..255
            int row = c0 + rloc;
            float s = 0.f, q2 = 0.f;
#pragma unroll
            for (int j = 0; j < 4; ++j) {
                int col = n0 + khalf + j * 16 + lr;
                float val = acc[ii][j][r] * inv[j];
                size_t off = (size_t)row * HWN + col;
                val += xb[off];
                s += val; q2 += val * val;
                xrb[off] = f2bf(val);
            }
#pragma unroll
            for (int m = 1; m <= 8; m <<= 1) {
                s += __shfl_xor(s, m, 64);
                q2 += __shfl_xor(q2, m, 64);
            }
            if (lr == 0) { rsS[wv & 1][rloc] = s; rqS[wv & 1][rloc] = q2; }
        }
    }
    __syncthreads();
    {
        size_t base = ((size_t)b * 8 + nn) * 1024;
        int rloc = t & 255;
        if (t < 256) rowpart[base + c0 + rloc]       = rsS[0][rloc] + rsS[1][rloc];
        else         rowpart[base + 512 + c0 + rloc] = rqS[0][rloc] + rqS[1][rloc];
    }
}

// ---------------- MFMA bf16 GEMM: C[b] = scale*(A @ Bt^T) (+bias)(+relu)(+resid)
template <bool OUTBF16, int BIASMODE /*0 none,1 row,2 col*/, bool RELU,
          int RESMODE /*0,1=f32,2=bf16*/>
__global__ __launch_bounds__(256, 4) void mfma_gemm(const unsigned short* __restrict__ A,
                                                 const unsigned short* __restrict__ Bt,
                                                 const float* __restrict__ bias,
                                                 const void* __restrict__ resid,
                                                 void* __restrict__ C,
                                                 int K, int lda, int ldb, int ldc,
                                                 long strideA, long strideB, long strideC,
                                                 float scale) {
    __shared__ __align__(16) unsigned short As[2][128 * 32];
    __shared__ __align__(16) unsigned short Bs[2][128 * 32];
    int b  = blockIdx.z;
    int m0 = blockIdx.y * 128;
    int n0 = blockIdx.x * 128;
    const unsigned short* Ab = A  + (size_t)b * strideA;
    const unsigned short* Bb = Bt + (size_t)b * strideB;
    int t = threadIdx.x;
    int wv = t >> 6, L = t & 63;
    int wm = (wv >> 1) * 64, wn = (wv & 1) * 64;
    int lr = L & 15, lq = L >> 4;
    int srow = t >> 2;                       // staged row 0..63 (per half)
    int gchunk = (t & 3) ^ ((t >> 3) & 3);   // global 16B chunk, swizzle-matched
    int skof = gchunk * 8;                   // bf16 elem offset in k
    int swz = (lr >> 1) & 3;                 // read-side swizzle

    int aoff[4], boff[4];
#pragma unroll
    for (int i = 0; i < 4; ++i) {
        aoff[i] = (wm + i * 16 + lr) * 32 + ((lq ^ swz) * 8);
        boff[i] = (wn + i * 16 + lr) * 32 + ((lq ^ swz) * 8);
    }

    const unsigned short* gA0 = Ab + (size_t)(m0 + srow) * lda + skof;
    const unsigned short* gA1 = Ab + (size_t)(m0 + 64 + srow) * lda + skof;
    const unsigned short* gB0 = Bb + (size_t)(n0 + srow) * ldb + skof;
    const unsigned short* gB1 = Bb + (size_t)(n0 + 64 + srow) * ldb + skof;

    f32x4 acc[4][4] = {};
    int nIter = K >> 5;

    gload_lds16(gA0, &As[0][t * 8]);
    gload_lds16(gA1, &As[0][64 * 32 + t * 8]);
    gload_lds16(gB0, &Bs[0][t * 8]);
    gload_lds16(gB1, &Bs[0][64 * 32 + t * 8]);

    int p = 0;
    for (int i = 0; i < nIter; ++i) {
        __syncthreads();
        if (i + 1 < nIter) {
            int ko = (i + 1) << 5;
            gload_lds16(gA0 + ko, &As[p ^ 1][t * 8]);
            gload_lds16(gA1 + ko, &As[p ^ 1][64 * 32 + t * 8]);
            gload_lds16(gB0 + ko, &Bs[p ^ 1][t * 8]);
            gload_lds16(gB1 + ko, &Bs[p ^ 1][64 * 32 + t * 8]);
        }
        bf16x8 af[4], bfr[4];
#pragma unroll
        for (int j = 0; j < 4; ++j) af[j]  = *(const bf16x8*)&As[p][aoff[j]];
#pragma unroll
        for (int j = 0; j < 4; ++j) bfr[j] = *(const bf16x8*)&Bs[p][boff[j]];
#pragma unroll
        for (int ii = 0; ii < 4; ++ii)
#pragma unroll
            for (int jj = 0; jj < 4; ++jj)
                acc[ii][jj] = __builtin_amdgcn_mfma_f32_16x16x32_bf16(af[ii], bfr[jj], acc[ii][jj], 0, 0, 0);
        p ^= 1;
    }

    // epilogue: lane L, reg r -> row = lq*4 + r, col = lr (within 16x16 tile)
#pragma unroll
    for (int i = 0; i < 4; ++i) {
#pragma unroll
        for (int r = 0; r < 4; ++r) {
            int row = m0 + wm + i * 16 + lq * 4 + r;
            float brow = (BIASMODE == 1) ? bias[row] : 0.f;
#pragma unroll
            for (int j = 0; j < 4; ++j) {
                int col = n0 + wn + j * 16 + lr;
                float v = acc[i][j][r] * scale;
                if (BIASMODE == 1) v += brow;
                if (BIASMODE == 2) v += bias[col];
                if (RELU) v = fmaxf(v, 0.f);
                size_t off = (size_t)b * strideC + (size_t)row * ldc + col;
                if (RESMODE == 1) v += ((const float*)resid)[off];
                if (RESMODE == 2) v += bf2f(((const unsigned short*)resid)[off]);
                if (OUTBF16) ((unsigned short*)C)[off] = f2bf(v);
                else         ((float*)C)[off] = v;
            }
        }
    }
}

extern "C" void kernel_launch(void* const* d_in, const int* in_sizes, int n_in,
                              void* d_out, int out_size, void* d_ws, size_t ws_size,
                              hipStream_t stream) {
    const float* x     = (const float*)d_in[0];
    const float* bn1_g = (const float*)d_in[1];
    const float* bn1_b = (const float*)d_in[2];
    const float* W_qkv = (const float*)d_in[3];
    const float* b_qkv = (const float*)d_in[4];
    const float* bn2_g = (const float*)d_in[5];
    const float* bn2_b = (const float*)d_in[6];
    const float* W1    = (const float*)d_in[7];
    const float* b1    = (const float*)d_in[8];
    const float* W2    = (const float*)d_in[9];
    const float* b2    = (const float*)d_in[10];
    float* out = (float*)d_out;
    char* ws = (char*)d_ws;

    // workspace layout (bytes):
    unsigned short* hT    = (unsigned short*)(ws);                 // 32 MB (hT -> ybnT)
    unsigned short* qkT   = (unsigned short*)(ws + 33554432);      // 8 MB
    unsigned short* v     = (unsigned short*)(ws + 41943040);      // 32 MB (v -> y1T)
    unsigned short* xr    = (unsigned short*)(ws + 142606336);     // 32 MB (bf16 xr)
    unsigned short* Wqkvb = (unsigned short*)(ws + 176160768);     // 640 KB
    unsigned short* W1b   = (unsigned short*)(ws + 176816128);     // 512 KB
    unsigned short* W2b   = (unsigned short*)(ws + 177340416);     // 512 KB
    float* stats = (float*)(ws + 177864704);                       // 2048 f32
    float* mean1 = stats,        *rstd1 = stats + 512;
    float* mean2 = stats + 1024, *rstd2 = stats + 1536;
    unsigned short* ybnT = hT;
    unsigned short* y1T  = v;
    // scratch aliased into hT region (hT dead between step 3b and step 8):
    float* rowpartBN = (float*)(ws + 1179648);   // [32*8][2][512] = 1 MB

    const long sHT = (long)HWN * CC;    // 1024*512
    const long sQK = (long)HWN * 128;   // 1024*128
    const long sV  = (long)CC * HWN;    // 512*1024

    // 0. weights -> bf16 (single launch)
    cvt3_kernel<<<(OO * CC + 2 * CC * CC) / 256, 256, 0, stream>>>(W_qkv, W1, W2, Wqkvb, W1b, W2b);
    // 1. bn1 stats (fp32 x)
    bn_stats_kernel<false><<<CC, 256, 0, stream>>>(x, mean1, rstd1);
    // 2. hT[b][s][c] = relu(bn1(x)) transposed, bf16
    bn_apply_t_kernel<true, false><<<dim3(16, 8, BB), 256, 0, stream>>>(x, mean1, rstd1, bn1_g, bn1_b, hT);
    // 3a. qkT[s][o'] = hT @ Wqk^T + b_qkv[o']   (M=1024, N=128, K=512), col bias
    mfma_gemm<true, 2, false, 0><<<dim3(1, 8, BB), 256, 0, stream>>>(
        hT, Wqkvb, b_qkv, nullptr, qkT, 512, 512, 512, 128, sHT, 0, sQK, 1.f);
    // 3b. v[c][s] = Wv @ h + b_qkv[128+c]       (M=512, N=1024, K=512), row bias
    mfma_gemm<true, 1, false, 0><<<dim3(8, 4, BB), 256, 0, stream>>>(
        Wqkvb + 128 * 512, hT, b_qkv + 128, nullptr, v, 512, 512, 512, 1024, 0, sHT, sV, 1.f);
    // 4-6. fused: E = exp(QK^T/8) on the fly, denom in-register, PV + x resid,
    //      bf16 xr out, fused bn2 partials; c-split (2 blocks/CU) + XCD remap
    fused_pv_kernel<<<dim3(16, 1, BB), 512, 0, stream>>>(qkT, v, x, xr, rowpartBN);
    // 7. bn2 stats from fused partials
    reduce_bnstats_kernel<<<2, 256, 0, stream>>>(rowpartBN, mean2, rstd2);
    // 8. ybnT[s][c] = bn2(xr) transposed, bf16 (aliases hT)
    bn_apply_t_kernel<false, true><<<dim3(16, 8, BB), 256, 0, stream>>>(xr, mean2, rstd2, bn2_g, bn2_b, ybnT);
    // 9. y1T[s][o] = relu(ybnT @ W1^T + b1)     (M=1024, N=512, K=512), col bias (aliases v)
    mfma_gemm<true, 2, true, 0><<<dim3(4, 8, BB), 256, 0, stream>>>(
        ybnT, W1b, b1, nullptr, y1T, 512, 512, 512, 512, sHT, 0, sHT, 1.f);
    // 10. out[c][s] = W2 @ y1T^T + b2 + xr(bf16) -> d_out fp32  (M=512, N=1024, K=512)
    mfma_gemm<false, 1, false, 2><<<dim3(8, 4, BB), 256, 0, stream>>>(
        W2b, y1T, b2, xr, out, 512, 512, 512, 1024, 0, sHT, sV, 1.f);
}